// Round 1
// baseline (115.357 us; speedup 1.0000x reference)
//
#include <hip/hip_runtime.h>
#include <math.h>

#define N_PL 16
#define NT   17      // N_PL+1
#define OBJ  10
#define NPAIR 55     // OBJ*(OBJ+1)/2
#define M    36
#define BLK  64

// plin lookup given normalized-weight table wn[17] and inclusive cumsum cs[17].
__device__ __forceinline__ float plin_eval(const float* wn, const float* cs, float x) {
    float y = 16.0f * x;
    int idx = (int)y;                 // trunc toward zero, x >= 0
    float f = y - (float)idx;         // fractional part
    int i0 = idx < N_PL ? idx : N_PL;
    int i1 = (idx + 1) < N_PL ? (idx + 1) : N_PL;
    return __builtin_fmaf(f, wn[i1], cs[i0]);
}

__global__ __launch_bounds__(BLK, 1) void counter_kernel(
    const float* __restrict__ boxes,   // [n,4,36]
    const float* __restrict__ attn,    // [n,36]
    const float* __restrict__ ws,      // [8,17]
    float* __restrict__ out,           // [n,11]
    int n)
{
    __shared__ float s_wn[8][NT];
    __shared__ float s_cs[8][NT];
    // per-thread scratch, [idx][tid] layout: lanes hit consecutive banks (2-way, free)
    __shared__ float s_att[OBJ][BLK];
    __shared__ float s_dedup[OBJ * OBJ][BLK];
    __shared__ float s_sc[NPAIR][BLK];     // packed upper-tri score (pre-division)
    __shared__ float s_rows[OBJ][BLK];     // row_sims, then 1/row_sims

    const int tid = threadIdx.x;

    // ---- build plin tables (lanes 0..7, one table each) ----
    if (tid < 8) {
        float w[NT];
        float sum = 0.f;
        #pragma unroll
        for (int k = 0; k < NT; ++k) { w[k] = fabsf(ws[tid * NT + k]); sum += w[k]; }
        float c = 0.f;
        #pragma unroll
        for (int k = 0; k < NT; ++k) {
            float v = w[k] / sum;
            s_wn[tid][k] = v;
            c += v;
            s_cs[tid][k] = c;
        }
    }
    __syncthreads();   // only barrier; everything below is thread-private

    const int s = blockIdx.x * BLK + tid;
    if (s >= n) return;

    // ---- top-10 of attention[s,:] (set matches jax top_k: strict > keeps earliest index) ----
    float tv[OBJ]; int ti[OBJ];
    #pragma unroll
    for (int k = 0; k < OBJ; ++k) { tv[k] = -__builtin_inff(); ti[k] = 0; }
    const float* arow = attn + (size_t)s * M;
    for (int m = 0; m < M; ++m) {
        float v = arow[m];
        if (v > tv[OBJ - 1]) {
            tv[OBJ - 1] = v; ti[OBJ - 1] = m;
            #pragma unroll
            for (int k = OBJ - 1; k > 0; --k) {
                bool sw = tv[k] > tv[k - 1];
                float fa = tv[k - 1], fb = tv[k];
                int   ia = ti[k - 1], ib = ti[k];
                tv[k - 1] = sw ? fb : fa;  tv[k] = sw ? fa : fb;
                ti[k - 1] = sw ? ib : ia;  ti[k] = sw ? ia : ib;
            }
        }
    }

    // ---- gather boxes, sigmoid(att), area; accumulate att_conf sum ----
    float ratt[OBJ], rx0[OBJ], ry0[OBJ], rx1[OBJ], ry1[OBJ], rarea[OBJ];
    const float* brow = boxes + (size_t)s * (4 * M);
    float mA = 0.f;
    #pragma unroll
    for (int k = 0; k < OBJ; ++k) {
        int id = ti[k];
        float x0 = brow[id];
        float y0 = brow[M + id];
        float x1 = brow[2 * M + id];
        float y1 = brow[3 * M + id];
        rx0[k] = x0; ry0[k] = y0; rx1[k] = x1; ry1[k] = y1;
        float wdt = x1 - x0; wdt = wdt > 0.f ? wdt : 0.f;
        float hgt = y1 - y0; hgt = hgt > 0.f ? hgt : 0.f;
        rarea[k] = wdt * hgt;
        float a = 1.f / (1.f + __expf(-tv[k]));
        ratt[k] = a;
        s_att[k][tid] = a;
        mA += fabsf(plin_eval(s_wn[5], s_cs[5], a) - 0.5f);
    }

    // ---- pass A (unrolled, i<=j): dist, dedup matrix, packed score, dist_conf sum ----
    float mD = 0.f;
    #pragma unroll
    for (int i = 0; i < OBJ; ++i) {
        #pragma unroll
        for (int j = i; j < OBJ; ++j) {
            const int q = i * OBJ - (i * (i - 1)) / 2 + (j - i);
            float mnx = fmaxf(rx0[i], rx0[j]);
            float mny = fmaxf(ry0[i], ry0[j]);
            float mxx = fminf(rx1[i], rx1[j]);
            float mxy = fminf(ry1[i], ry1[j]);
            float wx = mxx - mnx; wx = wx > 0.f ? wx : 0.f;
            float wy = mxy - mny; wy = wy > 0.f ? wy : 0.f;
            float inter = wx * wy;
            float un = rarea[i] + rarea[j] - inter + 1e-12f;
            float d = 1.f - inter * __builtin_amdgcn_rcpf(un);   // dist = 1 - IoU
            float relev = ratt[i] * ratt[j];
            float dd = plin_eval(s_wn[3], s_cs[3], relev) *
                       plin_eval(s_wn[4], s_cs[4], d);
            s_dedup[i * OBJ + j][tid] = dd;
            if (j > i) s_dedup[j * OBJ + i][tid] = dd;
            float scv = plin_eval(s_wn[0], s_cs[0], relev) *
                        plin_eval(s_wn[1], s_cs[1], d);
            s_sc[q][tid] = scv;
            float dc = fabsf(plin_eval(s_wn[6], s_cs[6], d) - 0.5f);
            mD += (j > i) ? 2.f * dc : dc;
        }
    }

    // ---- pass B: sim + row_sims (symmetric; diagonal = cs2[16]^11 in closed form) ----
    {
        float c16 = s_cs[2][N_PL];
        float c2 = c16 * c16, c4 = c2 * c2, c8 = c4 * c4;
        float diag = c8 * c2 * c16;   // ^11
        #pragma unroll
        for (int i = 0; i < OBJ; ++i) s_rows[i][tid] = diag;
    }
    for (int i = 0; i < OBJ - 1; ++i) {
        float ai = s_att[i][tid];
        float racc = 0.f;
        for (int j = i + 1; j < OBJ; ++j) {
            float p = plin_eval(s_wn[2], s_cs[2], 1.f - fabsf(ai - s_att[j][tid]));
            #pragma unroll
            for (int a = 0; a < OBJ; ++a) {
                float da = fabsf(s_dedup[a * OBJ + i][tid] - s_dedup[a * OBJ + j][tid]);
                p *= plin_eval(s_wn[2], s_cs[2], 1.f - da);
            }
            racc += p;
            s_rows[j][tid] += p;   // thread-private LDS slot, no race
        }
        s_rows[i][tid] += racc;
    }
    #pragma unroll
    for (int i = 0; i < OBJ; ++i)
        s_rows[i][tid] = __builtin_amdgcn_rcpf(s_rows[i][tid]);

    // ---- pass C: total = sum score/(r_i r_j) + sum correction ----
    float tot = 0.f;
    {
        int q = 0;
        for (int i = 0; i < OBJ; ++i) {
            float ai = s_att[i][tid];
            float rinv_i = s_rows[i][tid];
            for (int j = i; j < OBJ; ++j) {
                float t = s_sc[q][tid] * rinv_i * s_rows[j][tid];
                tot += (j > i) ? 2.f * t : t;
                ++q;
            }
            tot += plin_eval(s_wn[0], s_cs[0], ai * ai) * rinv_i;
        }
    }
    float total = sqrtf(tot + 1e-20f);

    // ---- confidence + one-hot output ----
    float conf = plin_eval(s_wn[7], s_cs[7], mA * 0.1f + mD * 0.01f);
    float scl = total < 0.f ? 0.f : (total > 10.f ? 10.f : total);
    int i0 = (int)scl;
    float f = scl - (float)i0;
    int lo = i0 < OBJ ? i0 : OBJ;
    int hi = (i0 + 1) < OBJ ? (i0 + 1) : OBJ;
    float* orow = out + (size_t)s * (OBJ + 1);
    #pragma unroll
    for (int c = 0; c <= OBJ; ++c) {
        float v = ((c == lo) ? (1.f - f) : 0.f) + ((c == hi) ? f : 0.f);
        orow[c] = v * conf;
    }
}

extern "C" void kernel_launch(void* const* d_in, const int* in_sizes, int n_in,
                              void* d_out, int out_size, void* d_ws, size_t ws_size,
                              hipStream_t stream) {
    const float* boxes = (const float*)d_in[0];
    const float* attn  = (const float*)d_in[1];
    const float* ws    = (const float*)d_in[2];
    float* out = (float*)d_out;
    int n = in_sizes[1] / M;
    int blocks = (n + BLK - 1) / BLK;
    hipLaunchKernelGGL(counter_kernel, dim3(blocks), dim3(BLK), 0, stream,
                       boxes, attn, ws, out, n);
}

// Round 2
// 87.854 us; speedup vs baseline: 1.3131x; 1.3131x over previous
//
#include <hip/hip_runtime.h>
#include <math.h>

#define N_PL 16
#define NT   17      // N_PL+1
#define OBJ  10
#define M    36
#define SPB  8       // samples per block (= 64/K lanes)
#define BLK  64      // one wave per block

// packed (i<<4)|j pair tables
__constant__ unsigned char c_p55[55] = {
 0x00,0x01,0x02,0x03,0x04,0x05,0x06,0x07,0x08,0x09,
 0x11,0x12,0x13,0x14,0x15,0x16,0x17,0x18,0x19,
 0x22,0x23,0x24,0x25,0x26,0x27,0x28,0x29,
 0x33,0x34,0x35,0x36,0x37,0x38,0x39,
 0x44,0x45,0x46,0x47,0x48,0x49,
 0x55,0x56,0x57,0x58,0x59,
 0x66,0x67,0x68,0x69,
 0x77,0x78,0x79,
 0x88,0x89,
 0x99};
__constant__ unsigned char c_p45[45] = {
 0x01,0x02,0x03,0x04,0x05,0x06,0x07,0x08,0x09,
 0x12,0x13,0x14,0x15,0x16,0x17,0x18,0x19,
 0x23,0x24,0x25,0x26,0x27,0x28,0x29,
 0x34,0x35,0x36,0x37,0x38,0x39,
 0x45,0x46,0x47,0x48,0x49,
 0x56,0x57,0x58,0x59,
 0x67,0x68,0x69,
 0x78,0x79,
 0x89};

// plin lookup: s_tab[0..135] = normalized weights wn[8][17], s_tab[136..271] = cumsum cs[8][17]
__device__ __forceinline__ float plin_tab(const float* s_tab, int t, float x) {
    const float* wn = s_tab + t * NT;
    const float* cs = s_tab + 136 + t * NT;
    float y = 16.0f * x;
    int idx = (int)y;                 // trunc toward zero
    float f = y - (float)idx;
    int i0 = idx < N_PL ? idx : N_PL;
    int i1 = (idx + 1) < N_PL ? (idx + 1) : N_PL;
    return __builtin_fmaf(f, wn[i1], cs[i0]);
}

// one-time (per launch) table normalization into d_ws
__global__ void prep_tables(const float* __restrict__ ws, float* __restrict__ tab) {
    int t = threadIdx.x;
    if (t < 8) {
        float w[NT]; float sum = 0.f;
        #pragma unroll
        for (int k = 0; k < NT; ++k) { w[k] = fabsf(ws[t * NT + k]); sum += w[k]; }
        float c = 0.f;
        #pragma unroll
        for (int k = 0; k < NT; ++k) {
            float v = w[k] / sum;
            tab[t * NT + k] = v;          // wn
            c += v;
            tab[136 + t * NT + k] = c;    // cs
        }
    }
}

__global__ __launch_bounds__(BLK, 4) void counter_kernel(
    const float* __restrict__ boxes,   // [n,4,36]
    const float* __restrict__ attn,    // [n,36]
    const float* __restrict__ tab,     // [272] prepped tables
    float* __restrict__ out,           // [n,11]
    int n)
{
    __shared__ float s_tab[272];
    __shared__ float s_att[OBJ][SPB];          // sigmoid(att) per selected slot
    __shared__ float s_box[5][OBJ][SPB];       // x0,y0,x1,y1,area
    __shared__ float s_dedup[OBJ * OBJ][SPB];  // full dedup matrix
    __shared__ float s_rowp[OBJ][BLK];         // per-thread row_sims partials
    __shared__ float s_rfin[OBJ][SPB];         // 1/row_sims

    const int tid = threadIdx.x;
    const int g = tid & 7;     // lane within sample group
    const int p = tid >> 3;    // sample slot in block

    #pragma unroll
    for (int k = 0; k < 5; ++k) {
        int idx = tid + k * BLK;
        if (idx < 272) s_tab[idx] = tab[idx];
    }
    #pragma unroll
    for (int i = 0; i < OBJ; ++i) s_rowp[i][tid] = 0.f;

    int s = blockIdx.x * SPB + p;
    const bool active = (s < n);
    if (!active) s = n - 1;    // clamp; store suppressed later

    // ---- load attn row (9 x float4), build order keys ----
    const float* arow = attn + (size_t)s * M;
    float v[M];
    #pragma unroll
    for (int k = 0; k < 9; ++k) {
        float4 t4 = ((const float4*)arow)[k];
        v[4*k+0] = t4.x; v[4*k+1] = t4.y; v[4*k+2] = t4.z; v[4*k+3] = t4.w;
    }
    // monotone float->uint map, then append (63-m) so ties break to earlier index (jax top_k)
    unsigned long long key[M];
    #pragma unroll
    for (int m = 0; m < M; ++m) {
        unsigned int b = __float_as_uint(v[m]);
        unsigned int u = b ^ (0x80000000u | (unsigned int)((int)b >> 31));
        key[m] = ((unsigned long long)u << 6) | (unsigned int)(63 - m);
    }
    unsigned long long myk[5] = {0ull,0ull,0ull,0ull,0ull};
    #pragma unroll
    for (int m = 0; m < M; ++m)
        if ((m & 7) == g) myk[m >> 3] = key[m];
    int rnk[5] = {0,0,0,0,0};
    #pragma unroll
    for (int m = 0; m < M; ++m) {
        #pragma unroll
        for (int k = 0; k < 5; ++k) rnk[k] += (key[m] > myk[k]) ? 1 : 0;
    }

    __syncthreads();   // tables ready; rowp zeroed

    // ---- scatter selected objects (rank<10 => unique slot = rank) ----
    float mA = 0.f;    // sum |plin5(att)-0.5| over my selected
    const float* brow = boxes + (size_t)s * (4 * M);
    #pragma unroll
    for (int k = 0; k < 5; ++k) {
        int e = g + 8 * k;
        if (e < M && rnk[k] < OBJ) {
            unsigned int u = (unsigned int)(myk[k] >> 6);
            unsigned int b = (u & 0x80000000u) ? (u ^ 0x80000000u) : ~u;
            float ve = __uint_as_float(b);
            float a = 1.f / (1.f + __expf(-ve));
            int r = rnk[k];
            s_att[r][p] = a;
            mA += fabsf(plin_tab(s_tab, 5, a) - 0.5f);
            float x0 = brow[e], y0 = brow[M + e], x1 = brow[2 * M + e], y1 = brow[3 * M + e];
            float bw = fmaxf(x1 - x0, 0.f), bh = fmaxf(y1 - y0, 0.f);
            s_box[0][r][p] = x0; s_box[1][r][p] = y0;
            s_box[2][r][p] = x1; s_box[3][r][p] = y1;
            s_box[4][r][p] = bw * bh;
        }
    }
    __syncthreads();

    // ---- pass A: my ~7 of 55 (i<=j) pairs: dist, dedup, score(reg), dist_conf ----
    float mD = 0.f;
    float sc_loc[7];
    #pragma unroll
    for (int t = 0; t < 7; ++t) {
        int q = g + 8 * t;
        bool act = (q < 55);
        int pk = c_p55[act ? q : 0];
        int i = pk >> 4, j = pk & 15;
        float x0i = s_box[0][i][p], y0i = s_box[1][i][p], x1i = s_box[2][i][p], y1i = s_box[3][i][p], ari = s_box[4][i][p];
        float x0j = s_box[0][j][p], y0j = s_box[1][j][p], x1j = s_box[2][j][p], y1j = s_box[3][j][p], arj = s_box[4][j][p];
        float wx = fminf(x1i, x1j) - fmaxf(x0i, x0j); wx = fmaxf(wx, 0.f);
        float wy = fminf(y1i, y1j) - fmaxf(y0i, y0j); wy = fmaxf(wy, 0.f);
        float inter = wx * wy;
        float un = ari + arj - inter + 1e-12f;
        float d = 1.f - inter * __builtin_amdgcn_rcpf(un);
        float ai = s_att[i][p], aj = s_att[j][p];
        float relev = ai * aj;
        float dd = plin_tab(s_tab, 3, relev) * plin_tab(s_tab, 4, d);
        sc_loc[t] = plin_tab(s_tab, 0, relev) * plin_tab(s_tab, 1, d);
        float dc = fabsf(plin_tab(s_tab, 6, d) - 0.5f);
        if (act) {
            s_dedup[i * OBJ + j][p] = dd;
            s_dedup[j * OBJ + i][p] = dd;
            mD += (i != j) ? 2.f * dc : dc;
        }
    }
    __syncthreads();

    // ---- pass B: my ~6 of 45 (i<j) pairs: sim product, accumulate row partials ----
    #pragma unroll
    for (int t = 0; t < 6; ++t) {
        int r = g + 8 * t;
        bool act = (r < 45);
        int pk = c_p45[act ? r : 0];
        int i = pk >> 4, j = pk & 15;
        float ai = s_att[i][p], aj = s_att[j][p];
        float prod = plin_tab(s_tab, 2, 1.f - fabsf(ai - aj));
        #pragma unroll
        for (int a = 0; a < OBJ; ++a) {
            float da = fabsf(s_dedup[a * OBJ + i][p] - s_dedup[a * OBJ + j][p]);
            prod *= plin_tab(s_tab, 2, 1.f - da);
        }
        if (act) {
            s_rowp[i][tid] += prod;   // thread-private column
            s_rowp[j][tid] += prod;
        }
    }
    __syncthreads();

    // ---- reduce row_sims across the 8 group lanes; diagonal = cs2[16]^11 ----
    {
        float c16 = s_tab[136 + 2 * NT + N_PL];
        float c2 = c16 * c16, c4 = c2 * c2, c8 = c4 * c4;
        float diag = c8 * c2 * c16;
        int base = tid & ~7;
        #pragma unroll
        for (int rep = 0; rep < 2; ++rep) {
            int i = g + 8 * rep;
            if (i < OBJ) {
                float sum = diag;
                #pragma unroll
                for (int l = 0; l < 8; ++l) sum += s_rowp[i][base + l];
                s_rfin[i][p] = 1.f / sum;
            }
        }
    }
    __syncthreads();

    // ---- pass C: total = sum w*sc*rinv_i*rinv_j + sum plin0(a^2)*rinv ----
    float tot = 0.f;
    #pragma unroll
    for (int t = 0; t < 7; ++t) {
        int q = g + 8 * t;
        bool act = (q < 55);
        int pk = c_p55[act ? q : 0];
        int i = pk >> 4, j = pk & 15;
        float term = sc_loc[t] * s_rfin[i][p] * s_rfin[j][p];
        if (act) tot += (i != j) ? 2.f * term : term;
    }
    #pragma unroll
    for (int rep = 0; rep < 2; ++rep) {
        int i = g + 8 * rep;
        if (i < OBJ) {
            float ai = s_att[i][p];
            tot += plin_tab(s_tab, 0, ai * ai) * s_rfin[i][p];
        }
    }
    float carg = mA * 0.1f + mD * 0.01f;
    // group-of-8 reductions (xor masks 1,2,4 stay within aligned 8-lane groups)
    tot  += __shfl_xor(tot, 1);  tot  += __shfl_xor(tot, 2);  tot  += __shfl_xor(tot, 4);
    carg += __shfl_xor(carg, 1); carg += __shfl_xor(carg, 2); carg += __shfl_xor(carg, 4);

    float total = sqrtf(tot + 1e-20f);
    float conf = plin_tab(s_tab, 7, carg);
    float scl = fminf(fmaxf(total, 0.f), 10.f);
    int i0 = (int)scl;
    float f = scl - (float)i0;
    int lo = i0 < OBJ ? i0 : OBJ;
    int hi = (i0 + 1) < OBJ ? (i0 + 1) : OBJ;

    if (active) {
        float* orow = out + (size_t)s * (OBJ + 1);
        {
            int c = g;
            float vv = ((c == lo) ? (1.f - f) : 0.f) + ((c == hi) ? f : 0.f);
            orow[c] = vv * conf;
        }
        if (g < 3) {
            int c = g + 8;
            float vv = ((c == lo) ? (1.f - f) : 0.f) + ((c == hi) ? f : 0.f);
            orow[c] = vv * conf;
        }
    }
}

extern "C" void kernel_launch(void* const* d_in, const int* in_sizes, int n_in,
                              void* d_out, int out_size, void* d_ws, size_t ws_size,
                              hipStream_t stream) {
    const float* boxes = (const float*)d_in[0];
    const float* attn  = (const float*)d_in[1];
    const float* ws    = (const float*)d_in[2];
    float* out = (float*)d_out;
    float* tab = (float*)d_ws;   // 272 floats
    int n = in_sizes[1] / M;
    hipLaunchKernelGGL(prep_tables, dim3(1), dim3(64), 0, stream, ws, tab);
    int blocks = (n + SPB - 1) / SPB;
    hipLaunchKernelGGL(counter_kernel, dim3(blocks), dim3(BLK), 0, stream,
                       boxes, attn, tab, out, n);
}